// Round 3
// baseline (12603.477 us; speedup 1.0000x reference)
//
#include <hip/hip_runtime.h>

// Problem dims
#define B_   2048
#define D_   256
#define K_   20
#define UD_  512
#define E_   64
#define H_   256
#define HID_ 512

typedef __attribute__((ext_vector_type(8))) short bf8;    // 8 x bf16 (4 VGPRs) MFMA A/B frag
typedef __attribute__((ext_vector_type(4))) float f32x4;  // MFMA C/D frag
typedef __attribute__((ext_vector_type(4))) float f4;

#define MFMA16(a,b,c) __builtin_amdgcn_mfma_f32_16x16x32_bf16(a, b, c, 0, 0, 0)

__device__ __forceinline__ unsigned short f2bf(float x) {
  unsigned u = __float_as_uint(x);
  u += 0x7fffu + ((u >> 16) & 1u);   // RNE
  return (unsigned short)(u >> 16);
}
__device__ __forceinline__ float bfu(unsigned short x) {
  return __uint_as_float(((unsigned)x) << 16);
}
__device__ __forceinline__ float sigf(float x)   { return 1.0f / (1.0f + __expf(-x)); }
__device__ __forceinline__ float tanhf_(float x) { return 1.0f - 2.0f / (__expf(2.0f * x) + 1.0f); }

// ---------------------------------------------------------------------------
// Manual grid barrier (regular launch; 256 blocks, all co-resident by
// construction: 0 LDS, __launch_bounds__(256,1) => >=1 block/CU on 256 CUs).
// bar[0] = arrival count, bar[1] = generation. Re-zeroed each launch via the
// in-stream memset (graph replays include it).
// ---------------------------------------------------------------------------
__device__ __forceinline__ void grid_barrier(unsigned* bar, unsigned target,
                                             int nblocks)
{
  __syncthreads();
  if (threadIdx.x == 0) {
    unsigned prev = __hip_atomic_fetch_add(&bar[0], 1u, __ATOMIC_ACQ_REL,
                                           __HIP_MEMORY_SCOPE_AGENT);
    if (prev == (unsigned)(nblocks - 1)) {
      __hip_atomic_store(&bar[0], 0u, __ATOMIC_RELAXED, __HIP_MEMORY_SCOPE_AGENT);
      __hip_atomic_store(&bar[1], target, __ATOMIC_RELEASE, __HIP_MEMORY_SCOPE_AGENT);
    } else {
      while (__hip_atomic_load(&bar[1], __ATOMIC_ACQUIRE,
                               __HIP_MEMORY_SCOPE_AGENT) < target) {
        __builtin_amdgcn_s_sleep(2);
      }
    }
  }
  __syncthreads();
}

// ---------------------------------------------------------------------------
// Pack a [N,K] row-major f32 weight into MFMA B-fragment order (bf16).
// ---------------------------------------------------------------------------
__global__ __launch_bounds__(256) void pack_w(const float* __restrict__ W,
    unsigned short* __restrict__ dst, int NT, int KTsrc, int KTtot, int kt0,
    int ldw, int Nsrc)
{
  int idx = blockIdx.x * 256 + threadIdx.x;
  int total = NT * KTsrc * 64;
  if (idx >= total) return;
  int l  = idx & 63;
  int fk = idx >> 6;
  int kt = fk % KTsrc;
  int nt = fk / KTsrc;
  int n = nt * 16 + (l & 15);
  int k = kt * 32 + ((l >> 4) * 8);
  bf8 o;
#pragma unroll
  for (int j = 0; j < 8; ++j)
    o[j] = (n < Nsrc) ? (short)f2bf(W[(size_t)n * ldw + k + j]) : (short)0;
  *(bf8*)(dst + (((size_t)(nt * KTtot + kt0 + kt)) * 64 + l) * 8) = o;
}

// f32 -> bf16 row-major convert (8 elems / thread)
__global__ __launch_bounds__(256) void cvt_bf(const float* __restrict__ src,
    unsigned short* __restrict__ dst, int n8)
{
  int i = blockIdx.x * 256 + threadIdx.x;
  if (i >= n8) return;
  const f4* s = (const f4*)(src + (size_t)i * 8);
  f4 v0 = s[0], v1 = s[1];
  bf8 o;
#pragma unroll
  for (int j = 0; j < 4; ++j) { o[j] = (short)f2bf(v0[j]); o[4 + j] = (short)f2bf(v1[j]); }
  *(bf8*)(dst + (size_t)i * 8) = o;
}

// ---------------------------------------------------------------------------
// Generic C = A @ W^T + bias (pre-pass FiLM GEMMs).
// ---------------------------------------------------------------------------
template<bool OUTBF>
__global__ __launch_bounds__(256) void gemm_bt(
    const unsigned short* __restrict__ A, int lda, int aoff,
    const unsigned short* __restrict__ Bp, int KT,
    void* __restrict__ Cptr, int ldc, int coff,
    const float* __restrict__ bias)
{
  int tid = threadIdx.x;
  int l = tid & 63, w = tid >> 6;
  int wr = w >> 1, wc = w & 1;
  int r0 = blockIdx.y * 64 + wr * 32;
  int n0 = blockIdx.x * 64 + wc * 32;
  int lr = l & 15, lk = (l >> 4) * 8;
  f32x4 acc[2][2] = {};
  const unsigned short* a0p = A + (size_t)(r0 + lr) * lda + aoff + lk;
  const unsigned short* a1p = A + (size_t)(r0 + 16 + lr) * lda + aoff + lk;
  int ntb = n0 >> 4;
  for (int kt = 0; kt < KT; ++kt) {
    bf8 a0 = *(const bf8*)(a0p + kt * 32);
    bf8 a1 = *(const bf8*)(a1p + kt * 32);
    bf8 b0 = *(const bf8*)(Bp + (((size_t)(ntb + 0) * KT + kt) * 64 + l) * 8);
    bf8 b1 = *(const bf8*)(Bp + (((size_t)(ntb + 1) * KT + kt) * 64 + l) * 8);
    acc[0][0] = MFMA16(a0, b0, acc[0][0]);
    acc[0][1] = MFMA16(a0, b1, acc[0][1]);
    acc[1][0] = MFMA16(a1, b0, acc[1][0]);
    acc[1][1] = MFMA16(a1, b1, acc[1][1]);
  }
#pragma unroll
  for (int mi = 0; mi < 2; ++mi)
#pragma unroll
  for (int nj = 0; nj < 2; ++nj)
#pragma unroll
  for (int r = 0; r < 4; ++r) {
    int row = r0 + mi * 16 + (l >> 4) * 4 + r;
    int n = n0 + nj * 16 + lr;
    float v = acc[mi][nj][r] + bias[n];
    if (OUTBF) ((unsigned short*)Cptr)[(size_t)row * ldc + coff + n] = f2bf(v);
    else       ((float*)Cptr)[(size_t)row * ldc + coff + n] = v;
  }
}

// LayerNorm(512) + SiLU over Hgb [2048,1024].
__global__ __launch_bounds__(256) void ln_silu(
    const float* __restrict__ Hgb, unsigned short* __restrict__ Hsi,
    const float* __restrict__ gw, const float* __restrict__ gb,
    const float* __restrict__ bw, const float* __restrict__ bb)
{
  int tid = threadIdx.x;
  int l = tid & 63, w = tid >> 6;
  int gwv = blockIdx.x * 4 + w;
  int row = gwv >> 1, br = gwv & 1;
  const float* base = Hgb + (size_t)row * 1024 + br * 512 + l * 8;
  f4 v0 = *(const f4*)base;
  f4 v1 = *(const f4*)(base + 4);
  float s1 = 0.f, s2 = 0.f;
#pragma unroll
  for (int j = 0; j < 4; ++j) { s1 += v0[j] + v1[j]; s2 += v0[j] * v0[j] + v1[j] * v1[j]; }
  for (int m = 1; m < 64; m <<= 1) { s1 += __shfl_xor(s1, m, 64); s2 += __shfl_xor(s2, m, 64); }
  float mean = s1 * (1.0f / 512.0f);
  float var  = s2 * (1.0f / 512.0f) - mean * mean;
  float rstd = rsqrtf(var + 1e-5f);
  const float* W  = br ? bw : gw;
  const float* Bb = br ? bb : gb;
  bf8 o;
#pragma unroll
  for (int j = 0; j < 8; ++j) {
    float x = (j < 4) ? v0[j] : v1[j - 4];
    float y = (x - mean) * rstd * W[l * 8 + j] + Bb[l * 8 + j];
    o[j] = (short)f2bf(y * sigf(y));
  }
  *(bf8*)(Hsi + (size_t)row * 1024 + br * 512 + l * 8) = o;
}

// ---------------------------------------------------------------------------
// Persistent kernel: the whole 2-layer LSTM recurrence + head.
// Grid = 256 blocks (1/CU) x 256 threads (4 waves).
// Block (rt=bx>>4, ct=bx&15): rows rt*128..+128, h-cols ct*16..+16.
// Phase p (0..256): L0 step p | L1 step p-1 | head step p-2, then grid barrier.
// c0/c1/logq live in registers (fixed tile ownership).
// ---------------------------------------------------------------------------
struct PParams {
  const unsigned short* embB;    // [K_, E_] bf16
  const unsigned short* gbB;     // [B_,128] bf16 (gam | bet)
  const unsigned short* E0;      // [B_, E_] bf16
  const unsigned short* W0p;     // packed wih0|whh0, NT=64, KT=10
  const unsigned short* W1p;     // packed wih1|whh1, NT=64, KT=16
  const unsigned short* Whp;     // packed head, NT=2, KT=8
  unsigned short* H0;            // 2 x [B_,H_] bf16 ping-pong
  unsigned short* H1;
  unsigned* bar;                 // grid barrier state (2 x u32, zeroed)
  const float* bih0; const float* bhh0;
  const float* bih1; const float* bhh1;
  const float* headb;
  const int* X;
  float* out;
};

__device__ __forceinline__ bf8 mod_frag(const unsigned short* e,
                                        const unsigned short* gb)
{
  bf8 ev = *(const bf8*)e;
  bf8 gv = *(const bf8*)gb;
  bf8 bv = *(const bf8*)(gb + 64);
  bf8 o;
#pragma unroll
  for (int j = 0; j < 8; ++j) {
    float x = bfu((unsigned short)ev[j]) * (1.0f + bfu((unsigned short)gv[j]))
            + bfu((unsigned short)bv[j]);
    o[j] = (short)f2bf(x);
  }
  return o;
}

__global__ __launch_bounds__(256, 1) void persistent(PParams P)
{
  const int tid = threadIdx.x;
  const int l = tid & 63, w = tid >> 6;
  const int lr = l & 15, lk = (l >> 4) * 8;
  const int bx = blockIdx.x;
  const int rt = bx >> 4, ct = bx & 15;
  const int r0 = rt * 128 + w * 32;
  const int c  = ct * 16 + lr;
  const size_t HN = (size_t)B_ * H_;
  const int rowA0 = r0 + lr, rowA1 = r0 + 16 + lr;

  const float bi0 = P.bih0[c]           + P.bhh0[c];
  const float bf0 = P.bih0[H_ + c]      + P.bhh0[H_ + c];
  const float bg0 = P.bih0[2 * H_ + c]  + P.bhh0[2 * H_ + c];
  const float bo0 = P.bih0[3 * H_ + c]  + P.bhh0[3 * H_ + c];
  const float bi1 = P.bih1[c]           + P.bhh1[c];
  const float bf1 = P.bih1[H_ + c]      + P.bhh1[H_ + c];
  const float bg1 = P.bih1[2 * H_ + c]  + P.bhh1[2 * H_ + c];
  const float bo1 = P.bih1[3 * H_ + c]  + P.bhh1[3 * H_ + c];
  const float hb0 = P.headb[lr];
  const float hb1 = (lr < 4) ? P.headb[16 + lr] : 0.f;

  float c0r[2][4] = {};
  float c1r[2][4] = {};
  float lq[2][4]  = {};

  for (int ph = 0; ph < 257; ++ph) {
    const unsigned short* h0r = P.H0 + ((size_t)((ph + 1) & 1)) * HN; // h0[ph-1]
    unsigned short*       h0w = P.H0 + ((size_t)(ph & 1)) * HN;       // h0[ph]
    const unsigned short* h1r = P.H1 + ((size_t)(ph & 1)) * HN;       // h1[ph-2]
    unsigned short*       h1w = P.H1 + ((size_t)((ph + 1) & 1)) * HN; // h1[ph-1]

    if (ph < D_) {
      // ---- layer-0 cell, step ph ----
      bf8 xa0[2], xa1[2];
      if (ph == 0) {
#pragma unroll
        for (int kt = 0; kt < 2; ++kt) {
          xa0[kt] = *(const bf8*)(P.E0 + (size_t)rowA0 * E_ + kt * 32 + lk);
          xa1[kt] = *(const bf8*)(P.E0 + (size_t)rowA1 * E_ + kt * 32 + lk);
        }
      } else {
        int tok0 = P.X[rowA0 * D_ + ph - 1];
        int tok1 = P.X[rowA1 * D_ + ph - 1];
#pragma unroll
        for (int kt = 0; kt < 2; ++kt) {
          int k0 = kt * 32 + lk;
          xa0[kt] = mod_frag(P.embB + tok0 * E_ + k0, P.gbB + (size_t)rowA0 * 128 + k0);
          xa1[kt] = mod_frag(P.embB + tok1 * E_ + k0, P.gbB + (size_t)rowA1 * 128 + k0);
        }
      }
      f32x4 acc[2][4] = {};
#pragma unroll
      for (int kt = 0; kt < 10; ++kt) {
        bf8 a0 = (kt < 2) ? xa0[kt]
                          : *(const bf8*)(h0r + (size_t)rowA0 * H_ + (kt - 2) * 32 + lk);
        bf8 a1 = (kt < 2) ? xa1[kt]
                          : *(const bf8*)(h0r + (size_t)rowA1 * H_ + (kt - 2) * 32 + lk);
#pragma unroll
        for (int g = 0; g < 4; ++g) {
          bf8 b = *(const bf8*)(P.W0p + (((size_t)((g * 16 + ct) * 10 + kt)) * 64 + l) * 8);
          acc[0][g] = MFMA16(a0, b, acc[0][g]);
          acc[1][g] = MFMA16(a1, b, acc[1][g]);
        }
      }
#pragma unroll
      for (int mi = 0; mi < 2; ++mi)
#pragma unroll
      for (int r = 0; r < 4; ++r) {
        int row = r0 + mi * 16 + (l >> 4) * 4 + r;
        float iv = sigf(acc[mi][0][r] + bi0);
        float fv = sigf(acc[mi][1][r] + bf0);
        float gv = tanhf_(acc[mi][2][r] + bg0);
        float ov = sigf(acc[mi][3][r] + bo0);
        float cn = fv * c0r[mi][r] + iv * gv;
        c0r[mi][r] = cn;
        h0w[(size_t)row * H_ + c] = f2bf(ov * tanhf_(cn));
      }
    }

    if (ph >= 1) {
      // ---- layer-1 cell, step ph-1 : A = [h0[ph-1] | h1[ph-2]] ----
      f32x4 acc[2][4] = {};
#pragma unroll
      for (int kt = 0; kt < 16; ++kt) {
        const unsigned short* s = (kt < 8) ? h0r : h1r;
        int ko = (kt & 7) * 32 + lk;
        bf8 a0 = *(const bf8*)(s + (size_t)rowA0 * H_ + ko);
        bf8 a1 = *(const bf8*)(s + (size_t)rowA1 * H_ + ko);
#pragma unroll
        for (int g = 0; g < 4; ++g) {
          bf8 b = *(const bf8*)(P.W1p + (((size_t)((g * 16 + ct) * 16 + kt)) * 64 + l) * 8);
          acc[0][g] = MFMA16(a0, b, acc[0][g]);
          acc[1][g] = MFMA16(a1, b, acc[1][g]);
        }
      }
#pragma unroll
      for (int mi = 0; mi < 2; ++mi)
#pragma unroll
      for (int r = 0; r < 4; ++r) {
        int row = r0 + mi * 16 + (l >> 4) * 4 + r;
        float iv = sigf(acc[mi][0][r] + bi1);
        float fv = sigf(acc[mi][1][r] + bf1);
        float gv = tanhf_(acc[mi][2][r] + bg1);
        float ov = sigf(acc[mi][3][r] + bo1);
        float cn = fv * c1r[mi][r] + iv * gv;
        c1r[mi][r] = cn;
        h1w[(size_t)row * H_ + c] = f2bf(ov * tanhf_(cn));
      }
    }

    if (ph >= 2 && ct == 0) {
      // ---- head, step th = ph-2, reading h1r = h1[ph-2] ----
      const int th = ph - 2;
      f32x4 acc0[2] = {{0,0,0,0},{0,0,0,0}}, acc1[2] = {{0,0,0,0},{0,0,0,0}};
#pragma unroll
      for (int kt = 0; kt < 8; ++kt) {
        bf8 b0 = *(const bf8*)(P.Whp + (((size_t)(0 * 8 + kt)) * 64 + l) * 8);
        bf8 b1 = *(const bf8*)(P.Whp + (((size_t)(1 * 8 + kt)) * 64 + l) * 8);
#pragma unroll
        for (int mi = 0; mi < 2; ++mi) {
          bf8 a = *(const bf8*)(h1r + (size_t)(r0 + mi * 16 + lr) * H_ + kt * 32 + lk);
          acc0[mi] = MFMA16(a, b0, acc0[mi]);
          acc1[mi] = MFMA16(a, b1, acc1[mi]);
        }
      }
#pragma unroll
      for (int mi = 0; mi < 2; ++mi)
#pragma unroll
      for (int r = 0; r < 4; ++r) {
        int row = r0 + mi * 16 + (l >> 4) * 4 + r;
        float v0 = acc0[mi][r] + hb0;
        float v1 = (lr < 4) ? (acc1[mi][r] + hb1) : -1e30f;
        float m = fmaxf(v0, v1);
#pragma unroll
        for (int msk = 1; msk < 16; msk <<= 1) m = fmaxf(m, __shfl_xor(m, msk, 64));
        float s = __expf(v0 - m) + ((lr < 4) ? __expf(v1 - m) : 0.f);
#pragma unroll
        for (int msk = 1; msk < 16; msk <<= 1) s += __shfl_xor(s, msk, 64);
        float lse = m + __logf(s);
        int tok = P.X[row * D_ + th];
        float lt = ((lr == tok) ? v0 : 0.f) + ((lr + 16 == tok) ? v1 : 0.f);
#pragma unroll
        for (int msk = 1; msk < 16; msk <<= 1) lt += __shfl_xor(lt, msk, 64);
        lq[mi][r] += lt - lse;
      }
    }

    grid_barrier(P.bar, (unsigned)(ph + 1), gridDim.x);
  }

  // ---- tail: head for step 255 (h1[255] is in buffer 1) + output write ----
  if (ct == 0) {
    const unsigned short* h1f = P.H1 + HN;
    f32x4 acc0[2] = {{0,0,0,0},{0,0,0,0}}, acc1[2] = {{0,0,0,0},{0,0,0,0}};
#pragma unroll
    for (int kt = 0; kt < 8; ++kt) {
      bf8 b0 = *(const bf8*)(P.Whp + (((size_t)(0 * 8 + kt)) * 64 + l) * 8);
      bf8 b1 = *(const bf8*)(P.Whp + (((size_t)(1 * 8 + kt)) * 64 + l) * 8);
#pragma unroll
      for (int mi = 0; mi < 2; ++mi) {
        bf8 a = *(const bf8*)(h1f + (size_t)(r0 + mi * 16 + lr) * H_ + kt * 32 + lk);
        acc0[mi] = MFMA16(a, b0, acc0[mi]);
        acc1[mi] = MFMA16(a, b1, acc1[mi]);
      }
    }
#pragma unroll
    for (int mi = 0; mi < 2; ++mi)
#pragma unroll
    for (int r = 0; r < 4; ++r) {
      int row = r0 + mi * 16 + (l >> 4) * 4 + r;
      float v0 = acc0[mi][r] + hb0;
      float v1 = (lr < 4) ? (acc1[mi][r] + hb1) : -1e30f;
      float m = fmaxf(v0, v1);
#pragma unroll
      for (int msk = 1; msk < 16; msk <<= 1) m = fmaxf(m, __shfl_xor(m, msk, 64));
      float s = __expf(v0 - m) + ((lr < 4) ? __expf(v1 - m) : 0.f);
#pragma unroll
      for (int msk = 1; msk < 16; msk <<= 1) s += __shfl_xor(s, msk, 64);
      float lse = m + __logf(s);
      int tok = P.X[row * D_ + 255];
      float lt = ((lr == tok) ? v0 : 0.f) + ((lr + 16 == tok) ? v1 : 0.f);
#pragma unroll
      for (int msk = 1; msk < 16; msk <<= 1) lt += __shfl_xor(lt, msk, 64);
      if (lr == 0) P.out[row] = lq[mi][r] + (lt - lse);
    }
  }
}

// ---------------------------------------------------------------------------
extern "C" void kernel_launch(void* const* d_in, const int* in_sizes, int n_in,
                              void* d_out, int out_size, void* d_ws, size_t ws_size,
                              hipStream_t stream)
{
  (void)in_sizes; (void)n_in; (void)out_size; (void)ws_size;
  const float* U    = (const float*)d_in[0];
  const int*   X    = (const int*)  d_in[1];
  const float* emb  = (const float*)d_in[2];
  const float* u0w  = (const float*)d_in[3];
  const float* u0b  = (const float*)d_in[4];
  const float* gw1  = (const float*)d_in[5];
  const float* gb1  = (const float*)d_in[6];
  const float* glnw = (const float*)d_in[7];
  const float* glnb = (const float*)d_in[8];
  const float* gw2  = (const float*)d_in[9];
  const float* gb2  = (const float*)d_in[10];
  const float* bw1  = (const float*)d_in[11];
  const float* bb1  = (const float*)d_in[12];
  const float* blnw = (const float*)d_in[13];
  const float* blnb = (const float*)d_in[14];
  const float* bw2  = (const float*)d_in[15];
  const float* bb2  = (const float*)d_in[16];
  const float* wih0 = (const float*)d_in[17];
  const float* whh0 = (const float*)d_in[18];
  const float* bih0 = (const float*)d_in[19];
  const float* bhh0 = (const float*)d_in[20];
  const float* wih1 = (const float*)d_in[21];
  const float* whh1 = (const float*)d_in[22];
  const float* bih1 = (const float*)d_in[23];
  const float* bhh1 = (const float*)d_in[24];
  const float* headw = (const float*)d_in[25];
  const float* headb = (const float*)d_in[26];
  float* out = (float*)d_out;

  char* ws = (char*)d_ws;
  size_t off = 0;
  auto alloc = [&](size_t bytes) -> void* {
    void* p = ws + off; off += (bytes + 255) & ~(size_t)255; return p;
  };
  unsigned short* W0p  = (unsigned short*)alloc((size_t)1024 * 320 * 2);
  unsigned short* W1p  = (unsigned short*)alloc((size_t)1024 * 512 * 2);
  unsigned short* Wg1p = (unsigned short*)alloc((size_t)512 * 512 * 2);
  unsigned short* Wb1p = (unsigned short*)alloc((size_t)512 * 512 * 2);
  unsigned short* Wg2p = (unsigned short*)alloc((size_t)64 * 512 * 2);
  unsigned short* Wb2p = (unsigned short*)alloc((size_t)64 * 512 * 2);
  unsigned short* Wu0p = (unsigned short*)alloc((size_t)64 * 512 * 2);
  unsigned short* Whp  = (unsigned short*)alloc((size_t)32 * 256 * 2);
  unsigned short* Ubf  = (unsigned short*)alloc((size_t)B_ * UD_ * 2);
  float*          Hgb  = (float*)alloc((size_t)B_ * 1024 * 4);
  unsigned short* Hsi  = (unsigned short*)alloc((size_t)B_ * 1024 * 2);
  float*          GamBet = (float*)alloc((size_t)B_ * 128 * 4);
  unsigned short* GamBetB = (unsigned short*)alloc((size_t)B_ * 128 * 2);
  unsigned short* embB = (unsigned short*)alloc((size_t)K_ * E_ * 2);
  unsigned short* E0   = (unsigned short*)alloc((size_t)B_ * E_ * 2);
  size_t zoff = off;
  unsigned short* H0   = (unsigned short*)alloc((size_t)2 * B_ * H_ * 2);
  unsigned short* H1   = (unsigned short*)alloc((size_t)2 * B_ * H_ * 2);
  unsigned*       bar  = (unsigned*)alloc(2 * sizeof(unsigned));
  size_t zbytes = off - zoff;

  hipMemsetAsync(ws + zoff, 0, zbytes, stream);

  auto pg = [](int tot) { return dim3((tot + 255) / 256); };
  // weight packs:                        W      dst   NT  KTs KTt kt0 ldw Nsrc
  pack_w<<<pg(64 * 2 * 64),  256, 0, stream>>>(wih0, W0p,  64,  2, 10, 0,  64, 1024);
  pack_w<<<pg(64 * 8 * 64),  256, 0, stream>>>(whh0, W0p,  64,  8, 10, 2, 256, 1024);
  pack_w<<<pg(64 * 8 * 64),  256, 0, stream>>>(wih1, W1p,  64,  8, 16, 0, 256, 1024);
  pack_w<<<pg(64 * 8 * 64),  256, 0, stream>>>(whh1, W1p,  64,  8, 16, 8, 256, 1024);
  pack_w<<<pg(32 * 16 * 64), 256, 0, stream>>>(gw1,  Wg1p, 32, 16, 16, 0, 512, 512);
  pack_w<<<pg(32 * 16 * 64), 256, 0, stream>>>(bw1,  Wb1p, 32, 16, 16, 0, 512, 512);
  pack_w<<<pg(4 * 16 * 64),  256, 0, stream>>>(gw2,  Wg2p,  4, 16, 16, 0, 512, 64);
  pack_w<<<pg(4 * 16 * 64),  256, 0, stream>>>(bw2,  Wb2p,  4, 16, 16, 0, 512, 64);
  pack_w<<<pg(4 * 16 * 64),  256, 0, stream>>>(u0w,  Wu0p,  4, 16, 16, 0, 512, 64);
  pack_w<<<pg(2 * 8 * 64),   256, 0, stream>>>(headw, Whp,  2,  8,  8, 0, 256, 20);
  cvt_bf<<<pg(B_ * UD_ / 8), 256, 0, stream>>>(U, Ubf, B_ * UD_ / 8);
  cvt_bf<<<pg(K_ * E_ / 8),  256, 0, stream>>>(emb, embB, K_ * E_ / 8);

  // FiLM branch hidden layers
  gemm_bt<false><<<dim3(8, 32), 256, 0, stream>>>(Ubf, UD_, 0, Wg1p, 16, Hgb, 1024, 0,   gb1);
  gemm_bt<false><<<dim3(8, 32), 256, 0, stream>>>(Ubf, UD_, 0, Wb1p, 16, Hgb, 1024, 512, bb1);
  ln_silu<<<1024, 256, 0, stream>>>(Hgb, Hsi, glnw, glnb, blnw, blnb);
  gemm_bt<false><<<dim3(1, 32), 256, 0, stream>>>(Hsi, 1024, 0,   Wg2p, 16, GamBet, 128, 0,  gb2);
  gemm_bt<false><<<dim3(1, 32), 256, 0, stream>>>(Hsi, 1024, 512, Wb2p, 16, GamBet, 128, 64, bb2);
  cvt_bf<<<pg(B_ * 128 / 8), 256, 0, stream>>>(GamBet, GamBetB, B_ * 128 / 8);
  gemm_bt<true><<<dim3(1, 32), 256, 0, stream>>>(Ubf, UD_, 0, Wu0p, 16, E0, E_, 0, u0b);

  // persistent recurrence (regular launch + manual device-scope barrier)
  PParams P;
  P.embB = embB; P.gbB = GamBetB; P.E0 = E0;
  P.W0p = W0p; P.W1p = W1p; P.Whp = Whp;
  P.H0 = H0; P.H1 = H1; P.bar = bar;
  P.bih0 = bih0; P.bhh0 = bhh0; P.bih1 = bih1; P.bhh1 = bhh1;
  P.headb = headb; P.X = X; P.out = out;
  persistent<<<dim3(256), dim3(256), 0, stream>>>(P);
}

// Round 4
// 9714.290 us; speedup vs baseline: 1.2974x; 1.2974x over previous
//
#include <hip/hip_runtime.h>

// Problem dims
#define B_   2048
#define D_   256
#define K_   20
#define UD_  512
#define E_   64
#define H_   256
#define HID_ 512

typedef __attribute__((ext_vector_type(8))) short bf8;    // 8 x bf16 (4 VGPRs) MFMA A/B frag
typedef __attribute__((ext_vector_type(4))) float f32x4;  // MFMA C/D frag
typedef __attribute__((ext_vector_type(4))) float f4;

#define MFMA16(a,b,c) __builtin_amdgcn_mfma_f32_16x16x32_bf16(a, b, c, 0, 0, 0)

__device__ __forceinline__ unsigned short f2bf(float x) {
  unsigned u = __float_as_uint(x);
  u += 0x7fffu + ((u >> 16) & 1u);   // RNE
  return (unsigned short)(u >> 16);
}
__device__ __forceinline__ float bfu(unsigned short x) {
  return __uint_as_float(((unsigned)x) << 16);
}
__device__ __forceinline__ float sigf(float x)   { return 1.0f / (1.0f + __expf(-x)); }
__device__ __forceinline__ float tanhf_(float x) { return 1.0f - 2.0f / (__expf(2.0f * x) + 1.0f); }

// ---------------------------------------------------------------------------
// Pack a [N,K] row-major f32 weight into MFMA B-fragment order (bf16).
// ---------------------------------------------------------------------------
__global__ __launch_bounds__(256) void pack_w(const float* __restrict__ W,
    unsigned short* __restrict__ dst, int NT, int KTsrc, int KTtot, int kt0,
    int ldw, int Nsrc)
{
  int idx = blockIdx.x * 256 + threadIdx.x;
  int total = NT * KTsrc * 64;
  if (idx >= total) return;
  int l  = idx & 63;
  int fk = idx >> 6;
  int kt = fk % KTsrc;
  int nt = fk / KTsrc;
  int n = nt * 16 + (l & 15);
  int k = kt * 32 + ((l >> 4) * 8);
  bf8 o;
#pragma unroll
  for (int j = 0; j < 8; ++j)
    o[j] = (n < Nsrc) ? (short)f2bf(W[(size_t)n * ldw + k + j]) : (short)0;
  *(bf8*)(dst + (((size_t)(nt * KTtot + kt0 + kt)) * 64 + l) * 8) = o;
}

// f32 -> bf16 row-major convert (8 elems / thread)
__global__ __launch_bounds__(256) void cvt_bf(const float* __restrict__ src,
    unsigned short* __restrict__ dst, int n8)
{
  int i = blockIdx.x * 256 + threadIdx.x;
  if (i >= n8) return;
  const f4* s = (const f4*)(src + (size_t)i * 8);
  f4 v0 = s[0], v1 = s[1];
  bf8 o;
#pragma unroll
  for (int j = 0; j < 4; ++j) { o[j] = (short)f2bf(v0[j]); o[4 + j] = (short)f2bf(v1[j]); }
  *(bf8*)(dst + (size_t)i * 8) = o;
}

// ---------------------------------------------------------------------------
// Generic C = A @ W^T + bias (pre-pass FiLM GEMMs).
// ---------------------------------------------------------------------------
template<bool OUTBF>
__global__ __launch_bounds__(256) void gemm_bt(
    const unsigned short* __restrict__ A, int lda, int aoff,
    const unsigned short* __restrict__ Bp, int KT,
    void* __restrict__ Cptr, int ldc, int coff,
    const float* __restrict__ bias)
{
  int tid = threadIdx.x;
  int l = tid & 63, w = tid >> 6;
  int wr = w >> 1, wc = w & 1;
  int r0 = blockIdx.y * 64 + wr * 32;
  int n0 = blockIdx.x * 64 + wc * 32;
  int lr = l & 15, lk = (l >> 4) * 8;
  f32x4 acc[2][2] = {};
  const unsigned short* a0p = A + (size_t)(r0 + lr) * lda + aoff + lk;
  const unsigned short* a1p = A + (size_t)(r0 + 16 + lr) * lda + aoff + lk;
  int ntb = n0 >> 4;
  for (int kt = 0; kt < KT; ++kt) {
    bf8 a0 = *(const bf8*)(a0p + kt * 32);
    bf8 a1 = *(const bf8*)(a1p + kt * 32);
    bf8 b0 = *(const bf8*)(Bp + (((size_t)(ntb + 0) * KT + kt) * 64 + l) * 8);
    bf8 b1 = *(const bf8*)(Bp + (((size_t)(ntb + 1) * KT + kt) * 64 + l) * 8);
    acc[0][0] = MFMA16(a0, b0, acc[0][0]);
    acc[0][1] = MFMA16(a0, b1, acc[0][1]);
    acc[1][0] = MFMA16(a1, b0, acc[1][0]);
    acc[1][1] = MFMA16(a1, b1, acc[1][1]);
  }
#pragma unroll
  for (int mi = 0; mi < 2; ++mi)
#pragma unroll
  for (int nj = 0; nj < 2; ++nj)
#pragma unroll
  for (int r = 0; r < 4; ++r) {
    int row = r0 + mi * 16 + (l >> 4) * 4 + r;
    int n = n0 + nj * 16 + lr;
    float v = acc[mi][nj][r] + bias[n];
    if (OUTBF) ((unsigned short*)Cptr)[(size_t)row * ldc + coff + n] = f2bf(v);
    else       ((float*)Cptr)[(size_t)row * ldc + coff + n] = v;
  }
}

// LayerNorm(512) + SiLU over Hgb [2048,1024].
__global__ __launch_bounds__(256) void ln_silu(
    const float* __restrict__ Hgb, unsigned short* __restrict__ Hsi,
    const float* __restrict__ gw, const float* __restrict__ gb,
    const float* __restrict__ bw, const float* __restrict__ bb)
{
  int tid = threadIdx.x;
  int l = tid & 63, w = tid >> 6;
  int gwv = blockIdx.x * 4 + w;
  int row = gwv >> 1, br = gwv & 1;
  const float* base = Hgb + (size_t)row * 1024 + br * 512 + l * 8;
  f4 v0 = *(const f4*)base;
  f4 v1 = *(const f4*)(base + 4);
  float s1 = 0.f, s2 = 0.f;
#pragma unroll
  for (int j = 0; j < 4; ++j) { s1 += v0[j] + v1[j]; s2 += v0[j] * v0[j] + v1[j] * v1[j]; }
  for (int m = 1; m < 64; m <<= 1) { s1 += __shfl_xor(s1, m, 64); s2 += __shfl_xor(s2, m, 64); }
  float mean = s1 * (1.0f / 512.0f);
  float var  = s2 * (1.0f / 512.0f) - mean * mean;
  float rstd = rsqrtf(var + 1e-5f);
  const float* W  = br ? bw : gw;
  const float* Bb = br ? bb : gb;
  bf8 o;
#pragma unroll
  for (int j = 0; j < 8; ++j) {
    float x = (j < 4) ? v0[j] : v1[j - 4];
    float y = (x - mean) * rstd * W[l * 8 + j] + Bb[l * 8 + j];
    o[j] = (short)f2bf(y * sigf(y));
  }
  *(bf8*)(Hsi + (size_t)row * 1024 + br * 512 + l * 8) = o;
}

// ---------------------------------------------------------------------------
// Persistent kernel, v2.
// 16 row-groups x 16 column-blocks. Group g owns rows g*128..+128; member ct
// owns h-cols ct*16..+16. Only group-local sync is needed (rows independent).
// Barrier: per-block release flag store (own cache line) + 16-lane acquire
// poll -- no contended RMW. Weights staged in LDS (120KB) once; h0/h1 A-frags
// loaded once per phase into registers and shared by L0/L1/head.
// Swizzle: bx = (g&7) + 8*((g>>3) + 2*ct)  => group on one XCD (bx%8 = g%8).
// ---------------------------------------------------------------------------
struct PParams {
  const unsigned short* embB;    // [K_, E_] bf16
  const unsigned short* gbB;     // [B_,128] bf16 (gam | bet)
  const unsigned short* E0;      // [B_, E_] bf16
  const unsigned short* W0p;     // packed wih0|whh0, NT=64, KT=10
  const unsigned short* W1p;     // packed wih1|whh1, NT=64, KT=16
  const unsigned short* Whp;     // packed head, NT=2, KT=8
  unsigned short* H0;            // 2 x [B_,H_] bf16 ping-pong
  unsigned short* H1;
  unsigned* flags;               // [16 groups][16 members][16 u32], zeroed
  const float* bih0; const float* bhh0;
  const float* bih1; const float* bhh1;
  const float* headb;
  const int* X;
  float* out;
};

__device__ __forceinline__ bf8 mod_frag(const unsigned short* e,
                                        const unsigned short* gb)
{
  bf8 ev = *(const bf8*)e;
  bf8 gv = *(const bf8*)gb;
  bf8 bv = *(const bf8*)(gb + 64);
  bf8 o;
#pragma unroll
  for (int j = 0; j < 8; ++j) {
    float x = bfu((unsigned short)ev[j]) * (1.0f + bfu((unsigned short)gv[j]))
            + bfu((unsigned short)bv[j]);
    o[j] = (short)f2bf(x);
  }
  return o;
}

// Group barrier: arrival = own-flag release store; wait = 16-lane acquire poll.
__device__ __forceinline__ void group_barrier(unsigned* gflags, int member,
                                              unsigned target)
{
  __syncthreads();   // all waves of this block done with reads/writes
  if (threadIdx.x == 0) {
    __hip_atomic_store(&gflags[member * 16], target, __ATOMIC_RELEASE,
                       __HIP_MEMORY_SCOPE_AGENT);
  }
  int lane = threadIdx.x & 63;
  if (lane < 16) {
    while (__hip_atomic_load(&gflags[lane * 16], __ATOMIC_ACQUIRE,
                             __HIP_MEMORY_SCOPE_AGENT) < target) {
      __builtin_amdgcn_s_sleep(1);
    }
  }
  // every wave polled (acquire) on its own -> no second __syncthreads needed
}

__global__ __launch_bounds__(256, 1) void persistent(PParams P)
{
  __shared__ __align__(16) unsigned short ldsw[120 * 512];  // 120 KB
  const int tid = threadIdx.x;
  const int l = tid & 63, w = tid >> 6;
  const int lr = l & 15, lk = (l >> 4) * 8;
  const int bx = blockIdx.x;
  const int gid = (bx & 7) + 8 * ((bx >> 3) & 1);
  const int ct  = bx >> 4;
  unsigned* gflags = P.flags + gid * 256;   // 16 members * 16-u32 stride

  // ---- stage weight slices into LDS (identical frag layout) ----
  for (int f = w; f < 104; f += 4) {
    const unsigned short* src;
    if (f < 40) {
      int g = f / 10, kt = f - g * 10;
      src = P.W0p + (((size_t)((g * 16 + ct) * 10 + kt)) * 64 + l) * 8;
    } else {
      int f1 = f - 40; int g = f1 >> 4, kt = f1 & 15;
      src = P.W1p + (((size_t)((g * 16 + ct) * 16 + kt)) * 64 + l) * 8;
    }
    *(bf8*)(ldsw + (size_t)f * 512 + l * 8) = *(const bf8*)src;
  }
  if (ct == 0) {
    for (int f = w; f < 16; f += 4)
      *(bf8*)(ldsw + (size_t)(104 + f) * 512 + l * 8) =
          *(const bf8*)(P.Whp + ((size_t)f * 64 + l) * 8);
  }
  __syncthreads();

  const int r0 = gid * 128 + w * 32;
  const int c  = ct * 16 + lr;
  const size_t HN = (size_t)B_ * H_;
  const int rowA0 = r0 + lr, rowA1 = r0 + 16 + lr;

  const float bi0 = P.bih0[c]           + P.bhh0[c];
  const float bf0 = P.bih0[H_ + c]      + P.bhh0[H_ + c];
  const float bg0 = P.bih0[2 * H_ + c]  + P.bhh0[2 * H_ + c];
  const float bo0 = P.bih0[3 * H_ + c]  + P.bhh0[3 * H_ + c];
  const float bi1 = P.bih1[c]           + P.bhh1[c];
  const float bf1 = P.bih1[H_ + c]      + P.bhh1[H_ + c];
  const float bg1 = P.bih1[2 * H_ + c]  + P.bhh1[2 * H_ + c];
  const float bo1 = P.bih1[3 * H_ + c]  + P.bhh1[3 * H_ + c];
  const float hb0 = P.headb[lr];
  const float hb1 = (lr < 4) ? P.headb[16 + lr] : 0.f;

  float c0r[2][4] = {};
  float c1r[2][4] = {};
  float lq[2][4]  = {};

  for (int ph = 0; ph <= 257; ++ph) {
    const unsigned short* h0r = P.H0 + ((size_t)((ph + 1) & 1)) * HN; // h0[ph-1]
    unsigned short*       h0w = P.H0 + ((size_t)(ph & 1)) * HN;       // h0[ph]
    const unsigned short* h1r = P.H1 + ((size_t)(ph & 1)) * HN;       // h1[ph-2]
    unsigned short*       h1w = P.H1 + ((size_t)((ph + 1) & 1)) * HN; // h1[ph-1]

    // ---- shared A-fragments for this phase (registers, loaded once) ----
    bf8 ha[8][2];    // h0[ph-1]
    bf8 h1a[8][2];   // h1[ph-2]
#pragma unroll
    for (int kt = 0; kt < 8; ++kt) {
      ha[kt][0]  = *(const bf8*)(h0r + (size_t)rowA0 * H_ + kt * 32 + lk);
      ha[kt][1]  = *(const bf8*)(h0r + (size_t)rowA1 * H_ + kt * 32 + lk);
      h1a[kt][0] = *(const bf8*)(h1r + (size_t)rowA0 * H_ + kt * 32 + lk);
      h1a[kt][1] = *(const bf8*)(h1r + (size_t)rowA1 * H_ + kt * 32 + lk);
    }

    if (ph < D_) {
      // ---- layer-0 cell, step ph ----
      bf8 xa0[2], xa1[2];
      if (ph == 0) {
#pragma unroll
        for (int kt = 0; kt < 2; ++kt) {
          xa0[kt] = *(const bf8*)(P.E0 + (size_t)rowA0 * E_ + kt * 32 + lk);
          xa1[kt] = *(const bf8*)(P.E0 + (size_t)rowA1 * E_ + kt * 32 + lk);
        }
      } else {
        int tok0 = P.X[rowA0 * D_ + ph - 1];
        int tok1 = P.X[rowA1 * D_ + ph - 1];
#pragma unroll
        for (int kt = 0; kt < 2; ++kt) {
          int k0 = kt * 32 + lk;
          xa0[kt] = mod_frag(P.embB + tok0 * E_ + k0, P.gbB + (size_t)rowA0 * 128 + k0);
          xa1[kt] = mod_frag(P.embB + tok1 * E_ + k0, P.gbB + (size_t)rowA1 * 128 + k0);
        }
      }
      f32x4 acc[2][4] = {};
#pragma unroll
      for (int kt = 0; kt < 10; ++kt) {
        bf8 a0 = (kt < 2) ? xa0[kt] : ha[kt - 2][0];
        bf8 a1 = (kt < 2) ? xa1[kt] : ha[kt - 2][1];
#pragma unroll
        for (int g = 0; g < 4; ++g) {
          bf8 b = *(const bf8*)(ldsw + (size_t)(g * 10 + kt) * 512 + l * 8);
          acc[0][g] = MFMA16(a0, b, acc[0][g]);
          acc[1][g] = MFMA16(a1, b, acc[1][g]);
        }
      }
#pragma unroll
      for (int mi = 0; mi < 2; ++mi)
#pragma unroll
      for (int r = 0; r < 4; ++r) {
        int row = r0 + mi * 16 + (l >> 4) * 4 + r;
        float iv = sigf(acc[mi][0][r] + bi0);
        float fv = sigf(acc[mi][1][r] + bf0);
        float gv = tanhf_(acc[mi][2][r] + bg0);
        float ov = sigf(acc[mi][3][r] + bo0);
        float cn = fv * c0r[mi][r] + iv * gv;
        c0r[mi][r] = cn;
        h0w[(size_t)row * H_ + c] = f2bf(ov * tanhf_(cn));
      }
    }

    if (ph >= 1 && ph <= 256) {
      // ---- layer-1 cell, step ph-1 : A = [h0[ph-1] | h1[ph-2]] ----
      f32x4 acc[2][4] = {};
#pragma unroll
      for (int kt = 0; kt < 16; ++kt) {
        bf8 a0 = (kt < 8) ? ha[kt][0] : h1a[kt - 8][0];
        bf8 a1 = (kt < 8) ? ha[kt][1] : h1a[kt - 8][1];
#pragma unroll
        for (int g = 0; g < 4; ++g) {
          bf8 b = *(const bf8*)(ldsw + (size_t)(40 + g * 16 + kt) * 512 + l * 8);
          acc[0][g] = MFMA16(a0, b, acc[0][g]);
          acc[1][g] = MFMA16(a1, b, acc[1][g]);
        }
      }
#pragma unroll
      for (int mi = 0; mi < 2; ++mi)
#pragma unroll
      for (int r = 0; r < 4; ++r) {
        int row = r0 + mi * 16 + (l >> 4) * 4 + r;
        float iv = sigf(acc[mi][0][r] + bi1);
        float fv = sigf(acc[mi][1][r] + bf1);
        float gv = tanhf_(acc[mi][2][r] + bg1);
        float ov = sigf(acc[mi][3][r] + bo1);
        float cn = fv * c1r[mi][r] + iv * gv;
        c1r[mi][r] = cn;
        h1w[(size_t)row * H_ + c] = f2bf(ov * tanhf_(cn));
      }
    }

    if (ph >= 2 && ct == 0) {
      // ---- head, step th = ph-2, A-frags = h1a (same rows/kt) ----
      const int th = ph - 2;
      f32x4 acc0[2] = {{0,0,0,0},{0,0,0,0}}, acc1[2] = {{0,0,0,0},{0,0,0,0}};
#pragma unroll
      for (int kt = 0; kt < 8; ++kt) {
        bf8 b0 = *(const bf8*)(ldsw + (size_t)(104 + kt) * 512 + l * 8);
        bf8 b1 = *(const bf8*)(ldsw + (size_t)(112 + kt) * 512 + l * 8);
#pragma unroll
        for (int mi = 0; mi < 2; ++mi) {
          acc0[mi] = MFMA16(h1a[kt][mi], b0, acc0[mi]);
          acc1[mi] = MFMA16(h1a[kt][mi], b1, acc1[mi]);
        }
      }
#pragma unroll
      for (int mi = 0; mi < 2; ++mi)
#pragma unroll
      for (int r = 0; r < 4; ++r) {
        int row = r0 + mi * 16 + (l >> 4) * 4 + r;
        float v0 = acc0[mi][r] + hb0;
        float v1 = (lr < 4) ? (acc1[mi][r] + hb1) : -1e30f;
        float m = fmaxf(v0, v1);
#pragma unroll
        for (int msk = 1; msk < 16; msk <<= 1) m = fmaxf(m, __shfl_xor(m, msk, 64));
        float s = __expf(v0 - m) + ((lr < 4) ? __expf(v1 - m) : 0.f);
#pragma unroll
        for (int msk = 1; msk < 16; msk <<= 1) s += __shfl_xor(s, msk, 64);
        float lse = m + __logf(s);
        int tok = P.X[row * D_ + th];
        float lt = ((lr == tok) ? v0 : 0.f) + ((lr + 16 == tok) ? v1 : 0.f);
#pragma unroll
        for (int msk = 1; msk < 16; msk <<= 1) lt += __shfl_xor(lt, msk, 64);
        lq[mi][r] += lt - lse;
        if (ph == 257 && lr == 0) P.out[row] = lq[mi][r];
      }
    }

    if (ph < 257) group_barrier(gflags, ct, (unsigned)(ph + 1));
  }
}

// ---------------------------------------------------------------------------
extern "C" void kernel_launch(void* const* d_in, const int* in_sizes, int n_in,
                              void* d_out, int out_size, void* d_ws, size_t ws_size,
                              hipStream_t stream)
{
  (void)in_sizes; (void)n_in; (void)out_size; (void)ws_size;
  const float* U    = (const float*)d_in[0];
  const int*   X    = (const int*)  d_in[1];
  const float* emb  = (const float*)d_in[2];
  const float* u0w  = (const float*)d_in[3];
  const float* u0b  = (const float*)d_in[4];
  const float* gw1  = (const float*)d_in[5];
  const float* gb1  = (const float*)d_in[6];
  const float* glnw = (const float*)d_in[7];
  const float* glnb = (const float*)d_in[8];
  const float* gw2  = (const float*)d_in[9];
  const float* gb2  = (const float*)d_in[10];
  const float* bw1  = (const float*)d_in[11];
  const float* bb1  = (const float*)d_in[12];
  const float* blnw = (const float*)d_in[13];
  const float* blnb = (const float*)d_in[14];
  const float* bw2  = (const float*)d_in[15];
  const float* bb2  = (const float*)d_in[16];
  const float* wih0 = (const float*)d_in[17];
  const float* whh0 = (const float*)d_in[18];
  const float* bih0 = (const float*)d_in[19];
  const float* bhh0 = (const float*)d_in[20];
  const float* wih1 = (const float*)d_in[21];
  const float* whh1 = (const float*)d_in[22];
  const float* bih1 = (const float*)d_in[23];
  const float* bhh1 = (const float*)d_in[24];
  const float* headw = (const float*)d_in[25];
  const float* headb = (const float*)d_in[26];
  float* out = (float*)d_out;

  char* ws = (char*)d_ws;
  size_t off = 0;
  auto alloc = [&](size_t bytes) -> void* {
    void* p = ws + off; off += (bytes + 255) & ~(size_t)255; return p;
  };
  unsigned short* W0p  = (unsigned short*)alloc((size_t)1024 * 320 * 2);
  unsigned short* W1p  = (unsigned short*)alloc((size_t)1024 * 512 * 2);
  unsigned short* Wg1p = (unsigned short*)alloc((size_t)512 * 512 * 2);
  unsigned short* Wb1p = (unsigned short*)alloc((size_t)512 * 512 * 2);
  unsigned short* Wg2p = (unsigned short*)alloc((size_t)64 * 512 * 2);
  unsigned short* Wb2p = (unsigned short*)alloc((size_t)64 * 512 * 2);
  unsigned short* Wu0p = (unsigned short*)alloc((size_t)64 * 512 * 2);
  unsigned short* Whp  = (unsigned short*)alloc((size_t)32 * 256 * 2);
  unsigned short* Ubf  = (unsigned short*)alloc((size_t)B_ * UD_ * 2);
  float*          Hgb  = (float*)alloc((size_t)B_ * 1024 * 4);
  unsigned short* Hsi  = (unsigned short*)alloc((size_t)B_ * 1024 * 2);
  float*          GamBet = (float*)alloc((size_t)B_ * 128 * 4);
  unsigned short* GamBetB = (unsigned short*)alloc((size_t)B_ * 128 * 2);
  unsigned short* embB = (unsigned short*)alloc((size_t)K_ * E_ * 2);
  unsigned short* E0   = (unsigned short*)alloc((size_t)B_ * E_ * 2);
  size_t zoff = off;
  unsigned short* H0   = (unsigned short*)alloc((size_t)2 * B_ * H_ * 2);
  unsigned short* H1   = (unsigned short*)alloc((size_t)2 * B_ * H_ * 2);
  unsigned*       flags = (unsigned*)alloc((size_t)16 * 256 * sizeof(unsigned));
  size_t zbytes = off - zoff;

  hipMemsetAsync(ws + zoff, 0, zbytes, stream);

  auto pg = [](int tot) { return dim3((tot + 255) / 256); };
  // weight packs:                        W      dst   NT  KTs KTt kt0 ldw Nsrc
  pack_w<<<pg(64 * 2 * 64),  256, 0, stream>>>(wih0, W0p,  64,  2, 10, 0,  64, 1024);
  pack_w<<<pg(64 * 8 * 64),  256, 0, stream>>>(whh0, W0p,  64,  8, 10, 2, 256, 1024);
  pack_w<<<pg(64 * 8 * 64),  256, 0, stream>>>(wih1, W1p,  64,  8, 16, 0, 256, 1024);
  pack_w<<<pg(64 * 8 * 64),  256, 0, stream>>>(whh1, W1p,  64,  8, 16, 8, 256, 1024);
  pack_w<<<pg(32 * 16 * 64), 256, 0, stream>>>(gw1,  Wg1p, 32, 16, 16, 0, 512, 512);
  pack_w<<<pg(32 * 16 * 64), 256, 0, stream>>>(bw1,  Wb1p, 32, 16, 16, 0, 512, 512);
  pack_w<<<pg(4 * 16 * 64),  256, 0, stream>>>(gw2,  Wg2p,  4, 16, 16, 0, 512, 64);
  pack_w<<<pg(4 * 16 * 64),  256, 0, stream>>>(bw2,  Wb2p,  4, 16, 16, 0, 512, 64);
  pack_w<<<pg(4 * 16 * 64),  256, 0, stream>>>(u0w,  Wu0p,  4, 16, 16, 0, 512, 64);
  pack_w<<<pg(2 * 8 * 64),   256, 0, stream>>>(headw, Whp,  2,  8,  8, 0, 256, 20);
  cvt_bf<<<pg(B_ * UD_ / 8), 256, 0, stream>>>(U, Ubf, B_ * UD_ / 8);
  cvt_bf<<<pg(K_ * E_ / 8),  256, 0, stream>>>(emb, embB, K_ * E_ / 8);

  // FiLM branch hidden layers
  gemm_bt<false><<<dim3(8, 32), 256, 0, stream>>>(Ubf, UD_, 0, Wg1p, 16, Hgb, 1024, 0,   gb1);
  gemm_bt<false><<<dim3(8, 32), 256, 0, stream>>>(Ubf, UD_, 0, Wb1p, 16, Hgb, 1024, 512, bb1);
  ln_silu<<<1024, 256, 0, stream>>>(Hgb, Hsi, glnw, glnb, blnw, blnb);
  gemm_bt<false><<<dim3(1, 32), 256, 0, stream>>>(Hsi, 1024, 0,   Wg2p, 16, GamBet, 128, 0,  gb2);
  gemm_bt<false><<<dim3(1, 32), 256, 0, stream>>>(Hsi, 1024, 512, Wb2p, 16, GamBet, 128, 64, bb2);
  cvt_bf<<<pg(B_ * 128 / 8), 256, 0, stream>>>(GamBet, GamBetB, B_ * 128 / 8);
  gemm_bt<true><<<dim3(1, 32), 256, 0, stream>>>(Ubf, UD_, 0, Wu0p, 16, E0, E_, 0, u0b);

  // persistent recurrence (regular launch + group-local flag barriers)
  PParams P;
  P.embB = embB; P.gbB = GamBetB; P.E0 = E0;
  P.W0p = W0p; P.W1p = W1p; P.Whp = Whp;
  P.H0 = H0; P.H1 = H1; P.flags = flags;
  P.bih0 = bih0; P.bhh0 = bhh0; P.bih1 = bih1; P.bhh1 = bhh1;
  P.headb = headb; P.X = X; P.out = out;
  persistent<<<dim3(256), dim3(256), 0, stream>>>(P);
}

// Round 5
// 3727.465 us; speedup vs baseline: 3.3812x; 2.6061x over previous
//
#include <hip/hip_runtime.h>

// Problem dims
#define B_   2048
#define D_   256
#define K_   20
#define UD_  512
#define E_   64
#define H_   256
#define HID_ 512

typedef __attribute__((ext_vector_type(8))) short bf8;    // 8 x bf16 (4 VGPRs) MFMA A/B frag
typedef __attribute__((ext_vector_type(4))) float f32x4;  // MFMA C/D frag
typedef __attribute__((ext_vector_type(4))) float f4;

#define MFMA16(a,b,c) __builtin_amdgcn_mfma_f32_16x16x32_bf16(a, b, c, 0, 0, 0)

// Device-coherent (LLC) accesses: sc1 bypasses L1/L2 -> no wbl2/inv needed.
#define GLD(dst, p)  asm volatile("global_load_dwordx4 %0, %1, off sc1" : "=v"(dst) : "v"(p))
#define GSTS(p, v)   asm volatile("global_store_short %0, %1, off sc1" :: "v"(p), "v"(v) : "memory")
#define GSTD(p, v)   asm volatile("global_store_dword %0, %1, off sc1" :: "v"(p), "v"(v) : "memory")
#define GLDD(dst, p) asm volatile("global_load_dword %0, %1, off sc1\n\ts_waitcnt vmcnt(0)" : "=v"(dst) : "v"(p) : "memory")

__device__ __forceinline__ unsigned short f2bf(float x) {
  unsigned u = __float_as_uint(x);
  u += 0x7fffu + ((u >> 16) & 1u);   // RNE
  return (unsigned short)(u >> 16);
}
__device__ __forceinline__ float bfu(unsigned short x) {
  return __uint_as_float(((unsigned)x) << 16);
}
__device__ __forceinline__ float sigf(float x)   { return 1.0f / (1.0f + __expf(-x)); }
__device__ __forceinline__ float tanhf_(float x) { return 1.0f - 2.0f / (__expf(2.0f * x) + 1.0f); }

// ---------------------------------------------------------------------------
// Pack a [N,K] row-major f32 weight into MFMA B-fragment order (bf16).
// ---------------------------------------------------------------------------
__global__ __launch_bounds__(256) void pack_w(const float* __restrict__ W,
    unsigned short* __restrict__ dst, int NT, int KTsrc, int KTtot, int kt0,
    int ldw, int Nsrc)
{
  int idx = blockIdx.x * 256 + threadIdx.x;
  int total = NT * KTsrc * 64;
  if (idx >= total) return;
  int l  = idx & 63;
  int fk = idx >> 6;
  int kt = fk % KTsrc;
  int nt = fk / KTsrc;
  int n = nt * 16 + (l & 15);
  int k = kt * 32 + ((l >> 4) * 8);
  bf8 o;
#pragma unroll
  for (int j = 0; j < 8; ++j)
    o[j] = (n < Nsrc) ? (short)f2bf(W[(size_t)n * ldw + k + j]) : (short)0;
  *(bf8*)(dst + (((size_t)(nt * KTtot + kt0 + kt)) * 64 + l) * 8) = o;
}

// f32 -> bf16 row-major convert (8 elems / thread)
__global__ __launch_bounds__(256) void cvt_bf(const float* __restrict__ src,
    unsigned short* __restrict__ dst, int n8)
{
  int i = blockIdx.x * 256 + threadIdx.x;
  if (i >= n8) return;
  const f4* s = (const f4*)(src + (size_t)i * 8);
  f4 v0 = s[0], v1 = s[1];
  bf8 o;
#pragma unroll
  for (int j = 0; j < 4; ++j) { o[j] = (short)f2bf(v0[j]); o[4 + j] = (short)f2bf(v1[j]); }
  *(bf8*)(dst + (size_t)i * 8) = o;
}

// ---------------------------------------------------------------------------
// Generic C = A @ W^T + bias (pre-pass FiLM GEMMs).
// ---------------------------------------------------------------------------
template<bool OUTBF>
__global__ __launch_bounds__(256) void gemm_bt(
    const unsigned short* __restrict__ A, int lda, int aoff,
    const unsigned short* __restrict__ Bp, int KT,
    void* __restrict__ Cptr, int ldc, int coff,
    const float* __restrict__ bias)
{
  int tid = threadIdx.x;
  int l = tid & 63, w = tid >> 6;
  int wr = w >> 1, wc = w & 1;
  int r0 = blockIdx.y * 64 + wr * 32;
  int n0 = blockIdx.x * 64 + wc * 32;
  int lr = l & 15, lk = (l >> 4) * 8;
  f32x4 acc[2][2] = {};
  const unsigned short* a0p = A + (size_t)(r0 + lr) * lda + aoff + lk;
  const unsigned short* a1p = A + (size_t)(r0 + 16 + lr) * lda + aoff + lk;
  int ntb = n0 >> 4;
  for (int kt = 0; kt < KT; ++kt) {
    bf8 a0 = *(const bf8*)(a0p + kt * 32);
    bf8 a1 = *(const bf8*)(a1p + kt * 32);
    bf8 b0 = *(const bf8*)(Bp + (((size_t)(ntb + 0) * KT + kt) * 64 + l) * 8);
    bf8 b1 = *(const bf8*)(Bp + (((size_t)(ntb + 1) * KT + kt) * 64 + l) * 8);
    acc[0][0] = MFMA16(a0, b0, acc[0][0]);
    acc[0][1] = MFMA16(a0, b1, acc[0][1]);
    acc[1][0] = MFMA16(a1, b0, acc[1][0]);
    acc[1][1] = MFMA16(a1, b1, acc[1][1]);
  }
#pragma unroll
  for (int mi = 0; mi < 2; ++mi)
#pragma unroll
  for (int nj = 0; nj < 2; ++nj)
#pragma unroll
  for (int r = 0; r < 4; ++r) {
    int row = r0 + mi * 16 + (l >> 4) * 4 + r;
    int n = n0 + nj * 16 + lr;
    float v = acc[mi][nj][r] + bias[n];
    if (OUTBF) ((unsigned short*)Cptr)[(size_t)row * ldc + coff + n] = f2bf(v);
    else       ((float*)Cptr)[(size_t)row * ldc + coff + n] = v;
  }
}

// LayerNorm(512) + SiLU over Hgb [2048,1024].
__global__ __launch_bounds__(256) void ln_silu(
    const float* __restrict__ Hgb, unsigned short* __restrict__ Hsi,
    const float* __restrict__ gw, const float* __restrict__ gb,
    const float* __restrict__ bw, const float* __restrict__ bb)
{
  int tid = threadIdx.x;
  int l = tid & 63, w = tid >> 6;
  int gwv = blockIdx.x * 4 + w;
  int row = gwv >> 1, br = gwv & 1;
  const float* base = Hgb + (size_t)row * 1024 + br * 512 + l * 8;
  f4 v0 = *(const f4*)base;
  f4 v1 = *(const f4*)(base + 4);
  float s1 = 0.f, s2 = 0.f;
#pragma unroll
  for (int j = 0; j < 4; ++j) { s1 += v0[j] + v1[j]; s2 += v0[j] * v0[j] + v1[j] * v1[j]; }
  for (int m = 1; m < 64; m <<= 1) { s1 += __shfl_xor(s1, m, 64); s2 += __shfl_xor(s2, m, 64); }
  float mean = s1 * (1.0f / 512.0f);
  float var  = s2 * (1.0f / 512.0f) - mean * mean;
  float rstd = rsqrtf(var + 1e-5f);
  const float* W  = br ? bw : gw;
  const float* Bb = br ? bb : gb;
  bf8 o;
#pragma unroll
  for (int j = 0; j < 8; ++j) {
    float x = (j < 4) ? v0[j] : v1[j - 4];
    float y = (x - mean) * rstd * W[l * 8 + j] + Bb[l * 8 + j];
    o[j] = (short)f2bf(y * sigf(y));
  }
  *(bf8*)(Hsi + (size_t)row * 1024 + br * 512 + l * 8) = o;
}

// ---------------------------------------------------------------------------
// Persistent kernel, v3. 16 groups (128 rows each) x 16 members (16 h-cols).
// All cross-block state (H0/H1, flags) via sc1 (device-coherent at LLC) -->
// no per-phase cache flush/invalidate. Ordering: stores drained (vmcnt(0) at
// __syncthreads) before the member's flag store; consumers poll flags then
// load. Weights LDS-resident; head rotates across members, merged by
// atomicAdd at the end. Correct for any workgroup->XCD assignment.
// ---------------------------------------------------------------------------
struct PParams {
  const unsigned short* embB;    // [K_, E_] bf16
  const unsigned short* gbB;     // [B_,128] bf16 (gam | bet)
  const unsigned short* E0;      // [B_, E_] bf16
  const unsigned short* W0p;     // packed wih0|whh0, NT=64, KT=10
  const unsigned short* W1p;     // packed wih1|whh1, NT=64, KT=16
  const unsigned short* Whp;     // packed head, NT=2, KT=8
  unsigned short* H0;            // 2 x [B_,H_] bf16 ping-pong
  unsigned short* H1;
  unsigned* flags;               // [16 groups][16 members][32 u32], zeroed
  const float* bih0; const float* bhh0;
  const float* bih1; const float* bhh1;
  const float* headb;
  const int* X;
  float* out;
};

__device__ __forceinline__ bf8 mod_frag(const unsigned short* e,
                                        const unsigned short* gb)
{
  bf8 ev = *(const bf8*)e;
  bf8 gv = *(const bf8*)gb;
  bf8 bv = *(const bf8*)(gb + 64);
  bf8 o;
#pragma unroll
  for (int j = 0; j < 8; ++j) {
    float x = bfu((unsigned short)ev[j]) * (1.0f + bfu((unsigned short)gv[j]))
            + bfu((unsigned short)bv[j]);
    o[j] = (short)f2bf(x);
  }
  return o;
}

// Group barrier: release = own-flag sc1 store after vmcnt(0)+block barrier;
// acquire = sc1 poll of the other 15 members' flags. No cache maintenance.
__device__ __forceinline__ void group_barrier(unsigned* flags, int gid,
                                              int mem, unsigned target)
{
  __syncthreads();                                   // all waves' vmem drained
  asm volatile("s_waitcnt vmcnt(0)" ::: "memory");
  if (threadIdx.x == 0) {
    unsigned* fp = flags + ((gid << 4) + mem) * 32;
    GSTD(fp, target);
  }
  int lane = threadIdx.x & 63;
  if (lane < 16 && lane != mem) {
    unsigned* fp = flags + ((gid << 4) + lane) * 32;
    unsigned v;
    do {
      __builtin_amdgcn_s_sleep(1);
      GLDD(v, fp);
    } while (v < target);
  }
  // wave reconverges after the masked loop -> no trailing __syncthreads needed
}

__global__ __launch_bounds__(256, 1) void persistent(PParams P)
{
  __shared__ __align__(16) unsigned short ldsw[120 * 512];  // 120 KB
  const int tid = threadIdx.x;
  const int l = tid & 63, w = tid >> 6;
  const int lr = l & 15, lk = (l >> 4) * 8;
  const int bx = blockIdx.x;
  const int gid = bx & 15;
  const int mem = bx >> 4;

  // ---- stage weight slices into LDS (identical frag layout) ----
  for (int f = w; f < 104; f += 4) {
    const unsigned short* src;
    if (f < 40) {
      int g = f / 10, kt = f - g * 10;
      src = P.W0p + (((size_t)((g * 16 + mem) * 10 + kt)) * 64 + l) * 8;
    } else {
      int f1 = f - 40; int g = f1 >> 4, kt = f1 & 15;
      src = P.W1p + (((size_t)((g * 16 + mem) * 16 + kt)) * 64 + l) * 8;
    }
    *(bf8*)(ldsw + (size_t)f * 512 + l * 8) = *(const bf8*)src;
  }
  for (int f = w; f < 16; f += 4)     // head weights in ALL blocks (rotation)
    *(bf8*)(ldsw + (size_t)(104 + f) * 512 + l * 8) =
        *(const bf8*)(P.Whp + ((size_t)f * 64 + l) * 8);
  __syncthreads();

  const int r0 = gid * 128 + w * 32;
  const int c  = mem * 16 + lr;
  const size_t HN = (size_t)B_ * H_;
  const int rowA0 = r0 + lr, rowA1 = r0 + 16 + lr;

  const float bi0 = P.bih0[c]           + P.bhh0[c];
  const float bf0 = P.bih0[H_ + c]      + P.bhh0[H_ + c];
  const float bg0 = P.bih0[2 * H_ + c]  + P.bhh0[2 * H_ + c];
  const float bo0 = P.bih0[3 * H_ + c]  + P.bhh0[3 * H_ + c];
  const float bi1 = P.bih1[c]           + P.bhh1[c];
  const float bf1 = P.bih1[H_ + c]      + P.bhh1[H_ + c];
  const float bg1 = P.bih1[2 * H_ + c]  + P.bhh1[2 * H_ + c];
  const float bo1 = P.bih1[3 * H_ + c]  + P.bhh1[3 * H_ + c];
  const float hb0 = P.headb[lr];
  const float hb1 = (lr < 4) ? P.headb[16 + lr] : 0.f;

  float c0r[2][4] = {};
  float c1r[2][4] = {};
  float lq[2][4]  = {};

  for (int ph = 0; ph <= 257; ++ph) {
    const unsigned short* h0r = P.H0 + ((size_t)((ph + 1) & 1)) * HN; // h0[ph-1]
    unsigned short*       h0w = P.H0 + ((size_t)(ph & 1)) * HN;       // h0[ph]
    const unsigned short* h1r = P.H1 + ((size_t)(ph & 1)) * HN;       // h1[ph-2]
    unsigned short*       h1w = P.H1 + ((size_t)((ph + 1) & 1)) * HN; // h1[ph-1]

    // ---- issue A-fragment loads (sc1, device-coherent) ----
    bf8 ha[8][2], h1a[8][2];
    {
      const unsigned short* pa0 = h0r + (size_t)rowA0 * H_ + lk;
      const unsigned short* pa1 = h0r + (size_t)rowA1 * H_ + lk;
      const unsigned short* pb0 = h1r + (size_t)rowA0 * H_ + lk;
      const unsigned short* pb1 = h1r + (size_t)rowA1 * H_ + lk;
#pragma unroll
      for (int kt = 0; kt < 8; ++kt) {
        GLD(ha[kt][0],  pa0 + kt * 32);
        GLD(ha[kt][1],  pa1 + kt * 32);
        GLD(h1a[kt][0], pb0 + kt * 32);
        GLD(h1a[kt][1], pb1 + kt * 32);
      }
    }

    // ---- xs fragments (VALU, overlaps load latency) ----
    bf8 xa0[2], xa1[2];
    if (ph < D_) {
      if (ph == 0) {
#pragma unroll
        for (int kt = 0; kt < 2; ++kt) {
          xa0[kt] = *(const bf8*)(P.E0 + (size_t)rowA0 * E_ + kt * 32 + lk);
          xa1[kt] = *(const bf8*)(P.E0 + (size_t)rowA1 * E_ + kt * 32 + lk);
        }
      } else {
        int tok0 = P.X[rowA0 * D_ + ph - 1];
        int tok1 = P.X[rowA1 * D_ + ph - 1];
#pragma unroll
        for (int kt = 0; kt < 2; ++kt) {
          int k0 = kt * 32 + lk;
          xa0[kt] = mod_frag(P.embB + tok0 * E_ + k0, P.gbB + (size_t)rowA0 * 128 + k0);
          xa1[kt] = mod_frag(P.embB + tok1 * E_ + k0, P.gbB + (size_t)rowA1 * 128 + k0);
        }
      }
    }
    asm volatile("s_waitcnt vmcnt(0)" ::: "memory");  // A-frags resident
    __builtin_amdgcn_sched_barrier(0);                // rule #18: pin MFMAs after

    if (ph < D_) {
      // ---- layer-0 cell, step ph ----
      f32x4 acc[2][4] = {};
#pragma unroll
      for (int kt = 0; kt < 10; ++kt) {
        bf8 a0 = (kt < 2) ? xa0[kt] : ha[kt - 2][0];
        bf8 a1 = (kt < 2) ? xa1[kt] : ha[kt - 2][1];
#pragma unroll
        for (int g = 0; g < 4; ++g) {
          bf8 b = *(const bf8*)(ldsw + (size_t)(g * 10 + kt) * 512 + l * 8);
          acc[0][g] = MFMA16(a0, b, acc[0][g]);
          acc[1][g] = MFMA16(a1, b, acc[1][g]);
        }
      }
#pragma unroll
      for (int mi = 0; mi < 2; ++mi) {
        unsigned short* hp = h0w + (size_t)(r0 + mi * 16 + (l >> 4) * 4) * H_ + c;
#pragma unroll
        for (int r = 0; r < 4; ++r) {
          float iv = sigf(acc[mi][0][r] + bi0);
          float fv = sigf(acc[mi][1][r] + bf0);
          float gv = tanhf_(acc[mi][2][r] + bg0);
          float ov = sigf(acc[mi][3][r] + bo0);
          float cn = fv * c0r[mi][r] + iv * gv;
          c0r[mi][r] = cn;
          unsigned short hv = f2bf(ov * tanhf_(cn));
          GSTS(hp + (size_t)r * H_, hv);
        }
      }
    }

    if (ph >= 1 && ph <= 256) {
      // ---- layer-1 cell, step ph-1 : A = [h0[ph-1] | h1[ph-2]] ----
      f32x4 acc[2][4] = {};
#pragma unroll
      for (int kt = 0; kt < 16; ++kt) {
        bf8 a0 = (kt < 8) ? ha[kt][0] : h1a[kt - 8][0];
        bf8 a1 = (kt < 8) ? ha[kt][1] : h1a[kt - 8][1];
#pragma unroll
        for (int g = 0; g < 4; ++g) {
          bf8 b = *(const bf8*)(ldsw + (size_t)(40 + g * 16 + kt) * 512 + l * 8);
          acc[0][g] = MFMA16(a0, b, acc[0][g]);
          acc[1][g] = MFMA16(a1, b, acc[1][g]);
        }
      }
#pragma unroll
      for (int mi = 0; mi < 2; ++mi) {
        unsigned short* hp = h1w + (size_t)(r0 + mi * 16 + (l >> 4) * 4) * H_ + c;
#pragma unroll
        for (int r = 0; r < 4; ++r) {
          float iv = sigf(acc[mi][0][r] + bi1);
          float fv = sigf(acc[mi][1][r] + bf1);
          float gv = tanhf_(acc[mi][2][r] + bg1);
          float ov = sigf(acc[mi][3][r] + bo1);
          float cn = fv * c1r[mi][r] + iv * gv;
          c1r[mi][r] = cn;
          unsigned short hv = f2bf(ov * tanhf_(cn));
          GSTS(hp + (size_t)r * H_, hv);
        }
      }
    }

    if (ph >= 2 && ((ph - 2) & 15) == mem) {
      // ---- head, step th = ph-2 (rotates across members) ----
      const int th = ph - 2;
      f32x4 acc0[2] = {{0,0,0,0},{0,0,0,0}}, acc1[2] = {{0,0,0,0},{0,0,0,0}};
#pragma unroll
      for (int kt = 0; kt < 8; ++kt) {
        bf8 b0 = *(const bf8*)(ldsw + (size_t)(104 + kt) * 512 + l * 8);
        bf8 b1 = *(const bf8*)(ldsw + (size_t)(112 + kt) * 512 + l * 8);
#pragma unroll
        for (int mi = 0; mi < 2; ++mi) {
          acc0[mi] = MFMA16(h1a[kt][mi], b0, acc0[mi]);
          acc1[mi] = MFMA16(h1a[kt][mi], b1, acc1[mi]);
        }
      }
#pragma unroll
      for (int mi = 0; mi < 2; ++mi)
#pragma unroll
      for (int r = 0; r < 4; ++r) {
        int row = r0 + mi * 16 + (l >> 4) * 4 + r;
        float v0 = acc0[mi][r] + hb0;
        float v1 = (lr < 4) ? (acc1[mi][r] + hb1) : -1e30f;
        float m = fmaxf(v0, v1);
#pragma unroll
        for (int msk = 1; msk < 16; msk <<= 1) m = fmaxf(m, __shfl_xor(m, msk, 64));
        float s = __expf(v0 - m) + ((lr < 4) ? __expf(v1 - m) : 0.f);
#pragma unroll
        for (int msk = 1; msk < 16; msk <<= 1) s += __shfl_xor(s, msk, 64);
        float lse = m + __logf(s);
        int tok = P.X[row * D_ + th];
        float lt = ((lr == tok) ? v0 : 0.f) + ((lr + 16 == tok) ? v1 : 0.f);
#pragma unroll
        for (int msk = 1; msk < 16; msk <<= 1) lt += __shfl_xor(lt, msk, 64);
        lq[mi][r] += lt - lse;
      }
    }

    if (ph < 257) group_barrier(P.flags, gid, mem, (unsigned)(ph + 1));
  }

  // ---- merge per-member head partials ----
#pragma unroll
  for (int mi = 0; mi < 2; ++mi)
#pragma unroll
  for (int r = 0; r < 4; ++r) {
    int row = r0 + mi * 16 + (l >> 4) * 4 + r;
    if (lr == 0) atomicAdd(&P.out[row], lq[mi][r]);
  }
}

// ---------------------------------------------------------------------------
extern "C" void kernel_launch(void* const* d_in, const int* in_sizes, int n_in,
                              void* d_out, int out_size, void* d_ws, size_t ws_size,
                              hipStream_t stream)
{
  (void)in_sizes; (void)n_in; (void)ws_size;
  const float* U    = (const float*)d_in[0];
  const int*   X    = (const int*)  d_in[1];
  const float* emb  = (const float*)d_in[2];
  const float* u0w  = (const float*)d_in[3];
  const float* u0b  = (const float*)d_in[4];
  const float* gw1  = (const float*)d_in[5];
  const float* gb1  = (const float*)d_in[6];
  const float* glnw = (const float*)d_in[7];
  const float* glnb = (const float*)d_in[8];
  const float* gw2  = (const float*)d_in[9];
  const float* gb2  = (const float*)d_in[10];
  const float* bw1  = (const float*)d_in[11];
  const float* bb1  = (const float*)d_in[12];
  const float* blnw = (const float*)d_in[13];
  const float* blnb = (const float*)d_in[14];
  const float* bw2  = (const float*)d_in[15];
  const float* bb2  = (const float*)d_in[16];
  const float* wih0 = (const float*)d_in[17];
  const float* whh0 = (const float*)d_in[18];
  const float* bih0 = (const float*)d_in[19];
  const float* bhh0 = (const float*)d_in[20];
  const float* wih1 = (const float*)d_in[21];
  const float* whh1 = (const float*)d_in[22];
  const float* bih1 = (const float*)d_in[23];
  const float* bhh1 = (const float*)d_in[24];
  const float* headw = (const float*)d_in[25];
  const float* headb = (const float*)d_in[26];
  float* out = (float*)d_out;

  char* ws = (char*)d_ws;
  size_t off = 0;
  auto alloc = [&](size_t bytes) -> void* {
    void* p = ws + off; off += (bytes + 255) & ~(size_t)255; return p;
  };
  unsigned short* W0p  = (unsigned short*)alloc((size_t)1024 * 320 * 2);
  unsigned short* W1p  = (unsigned short*)alloc((size_t)1024 * 512 * 2);
  unsigned short* Wg1p = (unsigned short*)alloc((size_t)512 * 512 * 2);
  unsigned short* Wb1p = (unsigned short*)alloc((size_t)512 * 512 * 2);
  unsigned short* Wg2p = (unsigned short*)alloc((size_t)64 * 512 * 2);
  unsigned short* Wb2p = (unsigned short*)alloc((size_t)64 * 512 * 2);
  unsigned short* Wu0p = (unsigned short*)alloc((size_t)64 * 512 * 2);
  unsigned short* Whp  = (unsigned short*)alloc((size_t)32 * 256 * 2);
  unsigned short* Ubf  = (unsigned short*)alloc((size_t)B_ * UD_ * 2);
  float*          Hgb  = (float*)alloc((size_t)B_ * 1024 * 4);
  unsigned short* Hsi  = (unsigned short*)alloc((size_t)B_ * 1024 * 2);
  float*          GamBet = (float*)alloc((size_t)B_ * 128 * 4);
  unsigned short* GamBetB = (unsigned short*)alloc((size_t)B_ * 128 * 2);
  unsigned short* embB = (unsigned short*)alloc((size_t)K_ * E_ * 2);
  unsigned short* E0   = (unsigned short*)alloc((size_t)B_ * E_ * 2);
  size_t zoff = off;
  unsigned short* H0   = (unsigned short*)alloc((size_t)2 * B_ * H_ * 2);
  unsigned short* H1   = (unsigned short*)alloc((size_t)2 * B_ * H_ * 2);
  unsigned*       flags = (unsigned*)alloc((size_t)16 * 16 * 32 * sizeof(unsigned));
  size_t zbytes = off - zoff;

  hipMemsetAsync(ws + zoff, 0, zbytes, stream);
  hipMemsetAsync(out, 0, (size_t)out_size * sizeof(float), stream);

  auto pg = [](int tot) { return dim3((tot + 255) / 256); };
  // weight packs:                        W      dst   NT  KTs KTt kt0 ldw Nsrc
  pack_w<<<pg(64 * 2 * 64),  256, 0, stream>>>(wih0, W0p,  64,  2, 10, 0,  64, 1024);
  pack_w<<<pg(64 * 8 * 64),  256, 0, stream>>>(whh0, W0p,  64,  8, 10, 2, 256, 1024);
  pack_w<<<pg(64 * 8 * 64),  256, 0, stream>>>(wih1, W1p,  64,  8, 16, 0, 256, 1024);
  pack_w<<<pg(64 * 8 * 64),  256, 0, stream>>>(whh1, W1p,  64,  8, 16, 8, 256, 1024);
  pack_w<<<pg(32 * 16 * 64), 256, 0, stream>>>(gw1,  Wg1p, 32, 16, 16, 0, 512, 512);
  pack_w<<<pg(32 * 16 * 64), 256, 0, stream>>>(bw1,  Wb1p, 32, 16, 16, 0, 512, 512);
  pack_w<<<pg(4 * 16 * 64),  256, 0, stream>>>(gw2,  Wg2p,  4, 16, 16, 0, 512, 64);
  pack_w<<<pg(4 * 16 * 64),  256, 0, stream>>>(bw2,  Wb2p,  4, 16, 16, 0, 512, 64);
  pack_w<<<pg(4 * 16 * 64),  256, 0, stream>>>(u0w,  Wu0p,  4, 16, 16, 0, 512, 64);
  pack_w<<<pg(2 * 8 * 64),   256, 0, stream>>>(headw, Whp,  2,  8,  8, 0, 256, 20);
  cvt_bf<<<pg(B_ * UD_ / 8), 256, 0, stream>>>(U, Ubf, B_ * UD_ / 8);
  cvt_bf<<<pg(K_ * E_ / 8),  256, 0, stream>>>(emb, embB, K_ * E_ / 8);

  // FiLM branch hidden layers
  gemm_bt<false><<<dim3(8, 32), 256, 0, stream>>>(Ubf, UD_, 0, Wg1p, 16, Hgb, 1024, 0,   gb1);
  gemm_bt<false><<<dim3(8, 32), 256, 0, stream>>>(Ubf, UD_, 0, Wb1p, 16, Hgb, 1024, 512, bb1);
  ln_silu<<<1024, 256, 0, stream>>>(Hgb, Hsi, glnw, glnb, blnw, blnb);
  gemm_bt<false><<<dim3(1, 32), 256, 0, stream>>>(Hsi, 1024, 0,   Wg2p, 16, GamBet, 128, 0,  gb2);
  gemm_bt<false><<<dim3(1, 32), 256, 0, stream>>>(Hsi, 1024, 512, Wb2p, 16, GamBet, 128, 64, bb2);
  cvt_bf<<<pg(B_ * 128 / 8), 256, 0, stream>>>(GamBet, GamBetB, B_ * 128 / 8);
  gemm_bt<true><<<dim3(1, 32), 256, 0, stream>>>(Ubf, UD_, 0, Wu0p, 16, E0, E_, 0, u0b);

  // persistent recurrence (regular launch + LLC-coherent group barriers)
  PParams P;
  P.embB = embB; P.gbB = GamBetB; P.E0 = E0;
  P.W0p = W0p; P.W1p = W1p; P.Whp = Whp;
  P.H0 = H0; P.H1 = H1; P.flags = flags;
  P.bih0 = bih0; P.bhh0 = bhh0; P.bih1 = bih1; P.bhh1 = bhh1;
  P.headb = headb; P.X = X; P.out = out;
  persistent<<<dim3(256), dim3(256), 0, stream>>>(P);
}